// Round 19
// baseline (3873.450 us; speedup 1.0000x reference)
//
#include <hip/hip_runtime.h>
#include <hip/hip_bf16.h>

#define TT 4096
#define FF 80
#define HH 64
#define NB 128
#define TB 256    // proj: timesteps per block
#define CT 8      // proj: timesteps per staging phase
#define XPAD 104  // proj LDS row stride in bf16 elems
#define LOG2E 1.44269504088896340736f
#define K2E   2.88539008177792681472f   // 2*log2(e)

using short8   = __attribute__((ext_vector_type(8))) short;    // 8 bf16 = 4 VGPR
using floatx4  = __attribute__((ext_vector_type(4))) float;
using floatx16 = __attribute__((ext_vector_type(16))) float;

__device__ __forceinline__ float sigm(float x)  { return __builtin_amdgcn_rcpf(1.0f + __expf(-x)); }
__device__ __forceinline__ float tanh_f(float x){ return 1.0f - 2.0f * __builtin_amdgcn_rcpf(1.0f + __expf(2.0f * x)); }

__device__ __forceinline__ unsigned short f2bf(float f) {    // RNE f32->bf16
    unsigned u = __builtin_bit_cast(unsigned, f);
    u += 0x7fffu + ((u >> 16) & 1u);
    return (unsigned short)(u >> 16);
}
__device__ __forceinline__ float bflo(unsigned u) { return __builtin_bit_cast(float, u << 16); }
__device__ __forceinline__ float bfhi(unsigned u) { return __builtin_bit_cast(float, u & 0xffff0000u); }
__device__ __forceinline__ unsigned packbf2(float a, float b) {
    return (unsigned)f2bf(a) | ((unsigned)f2bf(b) << 16);
}
__device__ __forceinline__ unsigned short cvt_bf16(float f) {
    unsigned r;
    asm("v_cvt_pk_bf16_f32 %0, %1, %2" : "=v"(r) : "v"(f), "v"(f));
    return (unsigned short)r;
}
// LDS-visibility-only barrier (multi-wave kernels only)
__device__ __forceinline__ void bar_lgkm() {
    asm volatile("s_waitcnt lgkmcnt(0)" ::: "memory");
    __builtin_amdgcn_s_barrier();
}
__device__ __forceinline__ floatx4 mfma16(short8 a, short8 b, floatx4 c) {
    return __builtin_amdgcn_mfma_f32_16x16x32_bf16(a, b, c, 0, 0, 0);
}
__device__ __forceinline__ floatx16 mfma32(short8 a, short8 b, floatx16 c) {
    return __builtin_amdgcn_mfma_f32_32x32x16_bf16(a, b, c, 0, 0, 0);
}
// activations on log2e-prescaled inputs (r13, vetted)
__device__ __forceinline__ float sigm_s(float s) {
    return __builtin_amdgcn_rcpf(1.0f + __builtin_amdgcn_exp2f(-s));
}
__device__ __forceinline__ float tanh_s(float s) {
    return fmaf(-2.0f, __builtin_amdgcn_rcpf(1.0f + __builtin_amdgcn_exp2f(s + s)), 1.0f);
}

// ---------------------------------------------------------------------------
// PROJ (MFMA): PRE[chain][t][p] bf16, log2e-scaled, with the SOLO-scan layout:
//   p = (u&31)*8 + (u>>5)*4 + gate   (lane l of the scan reads uint4 @ p=l*8)
// Otherwise identical to the r13/r17 proj (passed every round since r9).
// ---------------------------------------------------------------------------
__global__ __launch_bounds__(256, 1)
void lstm_proj_mfma(const float* __restrict__ x,
                    const float* __restrict__ w_ih_f, const float* __restrict__ b_ih_f,
                    const float* __restrict__ b_hh_f,
                    const float* __restrict__ w_ih_b, const float* __restrict__ b_ih_b,
                    const float* __restrict__ b_hh_b,
                    unsigned short* __restrict__ pre)
{
    const int blk   = blockIdx.x;
    const int ttile = blk & 15;
    const int dgrp  = blk >> 4;
    const int dir   = dgrp >> 3;
    const int bgrp  = dgrp & 7;
    const int tid   = threadIdx.x;
    const int wv    = tid >> 6;
    const int l     = tid & 63;
    const int b16   = l & 15;
    const int g     = l >> 4;
    const int t0    = ttile * TB;

    const float* __restrict__ wih = dir ? w_ih_b : w_ih_f;
    const float* __restrict__ bi  = dir ? b_ih_b : b_ih_f;
    const float* __restrict__ bh  = dir ? b_hh_b : b_hh_f;

    short8 Bf[4][3];
    float  bias[4];
    #pragma unroll
    for (int tp = 0; tp < 4; ++tp) {
        const int n = 64 * wv + 16 * tp + b16;
        bias[tp] = (bi[n] + bh[n]) * LOG2E;
        #pragma unroll
        for (int kap = 0; kap < 3; ++kap) {
            const int f0 = 32 * kap + 8 * g;
            float f[8];
            if (f0 < FF) {
                const float4 v0 = *reinterpret_cast<const float4*>(wih + n * FF + f0);
                const float4 v1 = *reinterpret_cast<const float4*>(wih + n * FF + f0 + 4);
                f[0]=v0.x; f[1]=v0.y; f[2]=v0.z; f[3]=v0.w;
                f[4]=v1.x; f[5]=v1.y; f[6]=v1.z; f[7]=v1.w;
            } else {
                #pragma unroll
                for (int j = 0; j < 8; ++j) f[j] = 0.0f;
            }
            short8 s;
            #pragma unroll
            for (int j = 0; j < 8; ++j) s[j] = (short)f2bf(f[j] * LOG2E);
            Bf[tp][kap] = s;
        }
    }

    __shared__ __align__(16) unsigned short xa[2][CT][16][XPAD];
    for (int i = tid; i < 2 * CT * 16 * XPAD / 2; i += 256)
        reinterpret_cast<unsigned*>(&xa[0][0][0][0])[i] = 0u;
    __syncthreads();

    const int nph = TB / CT;   // 32

    {   // prologue
        const int t0p = t0;
        const int te_base = dir ? (TT - CT - t0p) : t0p;
        float2 st[20];
        #pragma unroll
        for (int q = 0; q < 20; ++q) {
            const int i = q * 256 + tid;
            const int b = i / 320, r2 = i % 320;
            const int te_rel = r2 / 40, fq = r2 % 40;
            st[q] = *reinterpret_cast<const float2*>(
                x + ((size_t)(bgrp * 16 + b) * TT + te_base + te_rel) * FF + 2 * fq);
        }
        #pragma unroll
        for (int q = 0; q < 20; ++q) {
            const int i = q * 256 + tid;
            const int b = i / 320, r2 = i % 320;
            const int te_rel = r2 / 40, fq = r2 % 40;
            const int t_off = dir ? (CT - 1 - te_rel) : te_rel;
            *reinterpret_cast<unsigned*>(&xa[0][t_off][b][2 * fq]) = packbf2(st[q].x, st[q].y);
        }
    }
    __syncthreads();

    #pragma unroll 1
    for (int ph = 0; ph < nph; ++ph) {
        const int cur = ph & 1;
        const bool have = (ph + 1) < nph;

        float2 st[20];
        if (have) {
            const int t0p = t0 + (ph + 1) * CT;
            const int te_base = dir ? (TT - CT - t0p) : t0p;
            #pragma unroll
            for (int q = 0; q < 20; ++q) {
                const int i = q * 256 + tid;
                const int b = i / 320, r2 = i % 320;
                const int te_rel = r2 / 40, fq = r2 % 40;
                st[q] = *reinterpret_cast<const float2*>(
                    x + ((size_t)(bgrp * 16 + b) * TT + te_base + te_rel) * FF + 2 * fq);
            }
        }

        #pragma unroll
        for (int t_off = 0; t_off < CT; ++t_off) {
            short8 A[3];
            #pragma unroll
            for (int kap = 0; kap < 3; ++kap)
                A[kap] = *reinterpret_cast<const short8*>(&xa[cur][t_off][b16][32 * kap + 8 * g]);
            const int t = t0 + ph * CT + t_off;
            #pragma unroll
            for (int tp = 0; tp < 4; ++tp) {
                floatx4 acc = {bias[tp], bias[tp], bias[tp], bias[tp]};
                acc = mfma16(A[0], Bf[tp][0], acc);
                acc = mfma16(A[1], Bf[tp][1], acc);
                acc = mfma16(A[2], Bf[tp][2], acc);
                // gate = wv, unit u_ = 16*tp + b16 ; solo layout p
                const int u_ = 16 * tp + b16;
                const int p  = (u_ & 31) * 8 + (u_ >> 5) * 4 + wv;
                #pragma unroll
                for (int r = 0; r < 4; ++r) {
                    const int bb = dir * NB + bgrp * 16 + 4 * g + r;
                    pre[((size_t)bb * TT + t) * 256 + p] = f2bf(acc[r]);
                }
            }
        }

        if (have) {
            #pragma unroll
            for (int q = 0; q < 20; ++q) {
                const int i = q * 256 + tid;
                const int b = i / 320, r2 = i % 320;
                const int te_rel = r2 / 40, fq = r2 % 40;
                const int t_off = dir ? (CT - 1 - te_rel) : te_rel;
                *reinterpret_cast<unsigned*>(&xa[cur ^ 1][t_off][b][2 * fq]) = packbf2(st[q].x, st[q].y);
            }
        }
        bar_lgkm();
    }
}

// ---------------------------------------------------------------------------
// SCAN v12 (SOLO): 256 blocks x 64 threads = ONE WAVE per chain per CU.
// G[1x256] = h[1x64] @ W_hh^T via 8 tiles (32 cols) x 4 K-chunks of
// v_mfma_f32_32x32x16_bf16 (32 MFMAs, ~258cy issue). C layout (m74-verified):
// row 0 = reg 0, lanes 0..31 -> lane l holds all 4 gates of units l and l+32.
// NO BARRIER: h round-trips via a 384B LDS buffer with same-wave lgkmcnt
// ordering only — removes the ~290cy 4-wave rendezvous that dominated r17.
// A rows 1..31 read a zero region (r9 pattern). All vetted micro-opts kept:
// log2e prescale, c2-domain cell, cvt_pk store, pointer-bump depth-4 ring.
// LDS bytes: [0,128) h par0, [128,256) h par1, [256,384) zeros.
// ---------------------------------------------------------------------------
__global__ __launch_bounds__(64, 1)
void lstm_scan_solo(const unsigned short* __restrict__ pre,  // [256][TT][256] solo layout
                    const float* __restrict__ w_hh_f, const float* __restrict__ w_hh_b,
                    float* __restrict__ h_out)               // [256][64]
{
    const int chain = blockIdx.x;       // dir*128 + bat
    const int dir   = chain >> 7;
    const int l     = threadIdx.x;      // 0..63
    const int lh    = l >> 5;           // k-group (2 groups of 8)
    const int lc    = l & 31;           // A row / B col / C col
    const bool act  = (l < 32);         // cell owners: lanes 0..31, reg 0 = row 0

    const float* __restrict__ whh = dir ? w_hh_b : w_hh_f;

    // B-fragments (log2e-scaled): tile tau = gate*2 + uhalf, col n = gate*64 +
    // uhalf*32 + lc ; k = 16*kap + 8*lh + j.  8 tiles x 4 chunks.
    short8 B[8][4];
    #pragma unroll
    for (int tau = 0; tau < 8; ++tau) {
        const int n = (tau >> 1) * 64 + (tau & 1) * 32 + lc;
        #pragma unroll
        for (int kap = 0; kap < 4; ++kap) {
            const float* src = whh + n * HH + 16 * kap + 8 * lh;
            const float4 v0 = *reinterpret_cast<const float4*>(src);
            const float4 v1 = *reinterpret_cast<const float4*>(src + 4);
            short8 s;
            s[0]=(short)f2bf(v0.x*LOG2E); s[1]=(short)f2bf(v0.y*LOG2E);
            s[2]=(short)f2bf(v0.z*LOG2E); s[3]=(short)f2bf(v0.w*LOG2E);
            s[4]=(short)f2bf(v1.x*LOG2E); s[5]=(short)f2bf(v1.y*LOG2E);
            s[6]=(short)f2bf(v1.z*LOG2E); s[7]=(short)f2bf(v1.w*LOG2E);
            B[tau][kap] = s;
        }
    }

    __shared__ __align__(16) unsigned short hls[192];   // 384 B (layout above)
    for (int i = l; i < 96; i += 64)
        reinterpret_cast<unsigned*>(hls)[i] = 0u;
    __syncthreads();   // single wave: near-free; makes init ordering explicit

    // A-read bases: row-0 lanes (lc==0) read h; others read the zero region.
    // base(par) = b0 + par*bAdd ; chunk kap adds +32 (compile-time offset).
    const int b0   = (lc == 0 ? 16 * lh : 256 + 16 * lh);
    const int bAdd = (lc == 0 ? 128 : 0);

    // PRE ring: lane l (act) reads uint4 = 8 bf16 = all gates of units l, l+32.
    const uint4* __restrict__ prow =
        reinterpret_cast<const uint4*>(pre + (size_t)chain * TT * 256) + lc;
    uint4 pr[4] = {{0,0,0,0},{0,0,0,0},{0,0,0,0},{0,0,0,0}};
    const uint4 *pp0 = prow + 4 * 32, *pp1 = prow + 5 * 32,
                *pp2 = prow + 6 * 32, *pp3 = prow + 7 * 32;   // t stride = 32 uint4
    if (act) {
        pr[0] = prow[0 * 32]; pr[1] = prow[1 * 32];
        pr[2] = prow[2 * 32]; pr[3] = prow[3 * 32];
    }

    float c2A = 0.0f, hA = 0.0f;   // c2 = 2*log2e * c
    float c2B = 0.0f, hB = 0.0f;

    const char* lb = reinterpret_cast<const char*>(hls);
    char* lw = reinterpret_cast<char*>(hls);

    #pragma unroll 1
    for (int t = 0; t < TT; t += 4) {
        #pragma unroll
        for (int d = 0; d < 4; ++d) {
            const int cur = d & 1;   // (t+d)&1 since t%4==0

            // A fragments: 4 K-chunks (row-0 lanes real h, others zeros)
            const char* ab = lb + b0 + (cur ? bAdd : 0);
            const short8 A0 = *reinterpret_cast<const short8*>(ab);
            const short8 A1 = *reinterpret_cast<const short8*>(ab + 32);
            const short8 A2 = *reinterpret_cast<const short8*>(ab + 64);
            const short8 A3 = *reinterpret_cast<const short8*>(ab + 96);

            // capture PRE, rotate ring (pointer bump; tail reads land in slack)
            const uint4 pc = pr[d];
            if (act) {
                if (d == 0)      { pr[0] = *pp0; pp0 += 128; }
                else if (d == 1) { pr[1] = *pp1; pp1 += 128; }
                else if (d == 2) { pr[2] = *pp2; pp2 += 128; }
                else             { pr[3] = *pp3; pp3 += 128; }
            }

            // G = h @ W_hh^T : 8 tiles, 4-chained K each
            const floatx16 z = {0.f,0.f,0.f,0.f,0.f,0.f,0.f,0.f,
                                0.f,0.f,0.f,0.f,0.f,0.f,0.f,0.f};
            const floatx16 a0 = mfma32(A3,B[0][3], mfma32(A2,B[0][2], mfma32(A1,B[0][1], mfma32(A0,B[0][0], z))));
            const floatx16 a1 = mfma32(A3,B[1][3], mfma32(A2,B[1][2], mfma32(A1,B[1][1], mfma32(A0,B[1][0], z))));
            const floatx16 a2 = mfma32(A3,B[2][3], mfma32(A2,B[2][2], mfma32(A1,B[2][1], mfma32(A0,B[2][0], z))));
            const floatx16 a3 = mfma32(A3,B[3][3], mfma32(A2,B[3][2], mfma32(A1,B[3][1], mfma32(A0,B[3][0], z))));
            const floatx16 a4 = mfma32(A3,B[4][3], mfma32(A2,B[4][2], mfma32(A1,B[4][1], mfma32(A0,B[4][0], z))));
            const floatx16 a5 = mfma32(A3,B[5][3], mfma32(A2,B[5][2], mfma32(A1,B[5][1], mfma32(A0,B[5][0], z))));
            const floatx16 a6 = mfma32(A3,B[6][3], mfma32(A2,B[6][2], mfma32(A1,B[6][1], mfma32(A0,B[6][0], z))));
            const floatx16 a7 = mfma32(A3,B[7][3], mfma32(A2,B[7][2], mfma32(A1,B[7][1], mfma32(A0,B[7][0], z))));

            if (act) {
                // unit A = lc : tiles {0,2,4,6} ; unit B = lc+32 : tiles {1,3,5,7}
                const float giA = bflo(pc.x) + a0[0];
                const float gfA = bfhi(pc.x) + a2[0];
                const float ggA = bflo(pc.y) + a4[0];
                const float goA = bfhi(pc.y) + a6[0];
                const float giB = bflo(pc.z) + a1[0];
                const float gfB = bfhi(pc.z) + a3[0];
                const float ggB = bflo(pc.w) + a5[0];
                const float goB = bfhi(pc.w) + a7[0];

                {   // cell A
                    const float si = sigm_s(giA), sf = sigm_s(gfA);
                    const float tg = tanh_s(ggA), so = sigm_s(goA);
                    c2A = fmaf(sf, c2A, K2E * (si * tg));
                    const float th = fmaf(-2.0f,
                        __builtin_amdgcn_rcpf(1.0f + __builtin_amdgcn_exp2f(c2A)), 1.0f);
                    hA = so * th;
                }
                {   // cell B (independent -> ILP)
                    const float si = sigm_s(giB), sf = sigm_s(gfB);
                    const float tg = tanh_s(ggB), so = sigm_s(goB);
                    c2B = fmaf(sf, c2B, K2E * (si * tg));
                    const float th = fmaf(-2.0f,
                        __builtin_amdgcn_rcpf(1.0f + __builtin_amdgcn_exp2f(c2B)), 1.0f);
                    hB = so * th;
                }
                *reinterpret_cast<unsigned short*>(lw + 128 * (cur ^ 1) + 2 * lc)      = cvt_bf16(hA);
                *reinterpret_cast<unsigned short*>(lw + 128 * (cur ^ 1) + 64 + 2 * lc) = cvt_bf16(hB);
            }
            // NO barrier: same-wave DS ordering (compiler lgkmcnt) suffices.
        }
    }

    if (act) {
        h_out[(size_t)chain * HH + lc]      = hA;
        h_out[(size_t)chain * HH + 32 + lc] = hB;
    }
}

// ---------------------------------------------------------------------------
// Fallback: fully fused scan (round-1 kernel) if ws is too small for PRE.
// ---------------------------------------------------------------------------
__global__ __launch_bounds__(256, 1)
void lstm_scan_fused_kernel(const float* __restrict__ x,
                            const float* __restrict__ w_ih_f, const float* __restrict__ w_hh_f,
                            const float* __restrict__ b_ih_f, const float* __restrict__ b_hh_f,
                            const float* __restrict__ w_ih_b, const float* __restrict__ w_hh_b,
                            const float* __restrict__ b_ih_b, const float* __restrict__ b_hh_b,
                            float* __restrict__ h_out)
{
    const int blk = blockIdx.x;
    const int dir = blk >> 7;
    const int bat = blk & 127;
    const int tid = threadIdx.x;
    const int wv  = tid >> 6;
    const int ln  = tid & 63;

    const float* __restrict__ w_ih = dir ? w_ih_b : w_ih_f;
    const float* __restrict__ w_hh = dir ? w_hh_b : w_hh_f;
    const float* __restrict__ b_ih = dir ? b_ih_b : b_ih_f;
    const float* __restrict__ b_hh = dir ? b_hh_b : b_hh_f;

    float wi[FF], wh[HH];
    #pragma unroll
    for (int f = 0; f < FF; ++f) wi[f] = w_ih[tid * FF + f];
    #pragma unroll
    for (int j = 0; j < HH; ++j) wh[j] = w_hh[tid * HH + j];
    const float bias = b_ih[tid] + b_hh[tid];

    __shared__ float xs[2][FF];
    __shared__ float hbuf[4][HH];
    __shared__ float gbuf[2][256];

    const float* __restrict__ xrow = x + (size_t)bat * (TT * FF);
    float c = 0.0f, hreg = 0.0f;
    hbuf[wv][ln] = 0.0f;

    float xA = 0.0f;
    if (tid < FF) {
        xs[0][tid] = xrow[(size_t)(dir ? (TT - 1) : 0) * FF + tid];
        xA         = xrow[(size_t)(dir ? (TT - 2) : 1) * FF + tid];
    }
    __syncthreads();

    #pragma unroll 1
    for (int t = 0; t < TT; ++t) {
        const int cur = t & 1, nxt = cur ^ 1;
        float a0 = 0.f, a1 = 0.f, a2 = 0.f, a3 = 0.f;
        const float4* xs4 = reinterpret_cast<const float4*>(xs[cur]);
        #pragma unroll
        for (int f = 0; f < FF / 4; ++f) {
            float4 v = xs4[f];
            a0 = fmaf(wi[4*f+0], v.x, a0);
            a1 = fmaf(wi[4*f+1], v.y, a1);
            a2 = fmaf(wi[4*f+2], v.z, a2);
            a3 = fmaf(wi[4*f+3], v.w, a3);
        }
        const float4* hb4 = reinterpret_cast<const float4*>(hbuf[wv]);
        #pragma unroll
        for (int j = 0; j < HH / 4; ++j) {
            float4 v = hb4[j];
            a0 = fmaf(wh[4*j+0], v.x, a0);
            a1 = fmaf(wh[4*j+1], v.y, a1);
            a2 = fmaf(wh[4*j+2], v.z, a2);
            a3 = fmaf(wh[4*j+3], v.w, a3);
        }
        gbuf[cur][tid] = ((a0 + a1) + (a2 + a3)) + bias;

        if (tid < FF) {
            if (t + 1 < TT) xs[nxt][tid] = xA;
            if (t + 2 < TT) xA = xrow[(size_t)(dir ? (TT - 3 - t) : (t + 2)) * FF + tid];
        }
        __syncthreads();

        const float gi = gbuf[cur][ln];
        const float gf = gbuf[cur][64 + ln];
        const float gg = gbuf[cur][128 + ln];
        const float go = gbuf[cur][192 + ln];
        c    = sigm(gf) * c + sigm(gi) * tanh_f(gg);
        hreg = sigm(go) * tanh_f(c);
        hbuf[wv][ln] = hreg;
    }

    if (tid < HH) h_out[(size_t)(dir * 128 + bat) * HH + tid] = hreg;
}

__global__ __launch_bounds__(64, 1)
void fc_kernel(const float* __restrict__ h_out,   // [2][NB][HH]
               const float* __restrict__ w_fc,    // [8][128]
               const float* __restrict__ b_fc,    // [8]
               float* __restrict__ out)           // [NB][8]
{
    const int b = blockIdx.x;
    const int o = threadIdx.x;
    if (o < 8) {
        float acc = b_fc[o];
        #pragma unroll 4
        for (int j = 0; j < HH; ++j)
            acc = fmaf(h_out[(size_t)b * HH + j], w_fc[o * 128 + j], acc);
        #pragma unroll 4
        for (int j = 0; j < HH; ++j)
            acc = fmaf(h_out[(size_t)(NB + b) * HH + j], w_fc[o * 128 + 64 + j], acc);
        out[b * 8 + o] = acc;
    }
}

extern "C" void kernel_launch(void* const* d_in, const int* in_sizes, int n_in,
                              void* d_out, int out_size, void* d_ws, size_t ws_size,
                              hipStream_t stream) {
    const float* x      = (const float*)d_in[0];
    const float* w_ih_f = (const float*)d_in[2];
    const float* w_hh_f = (const float*)d_in[3];
    const float* b_ih_f = (const float*)d_in[4];
    const float* b_hh_f = (const float*)d_in[5];
    const float* w_ih_b = (const float*)d_in[6];
    const float* w_hh_b = (const float*)d_in[7];
    const float* b_ih_b = (const float*)d_in[8];
    const float* b_hh_b = (const float*)d_in[9];
    const float* w_fc   = (const float*)d_in[10];
    const float* b_fc   = (const float*)d_in[11];
    float* out = (float*)d_out;

    const size_t pre_bytes = (size_t)2 * NB * TT * 256 * 2;   // 512 MiB bf16
    const size_t need      = pre_bytes + 64 * 1024;

    if (ws_size >= need) {
        unsigned short* pre = (unsigned short*)d_ws;
        float* h_out = (float*)((char*)d_ws + pre_bytes);
        lstm_proj_mfma<<<dim3(256), dim3(256), 0, stream>>>(
            x, w_ih_f, b_ih_f, b_hh_f, w_ih_b, b_ih_b, b_hh_b, pre);
        lstm_scan_solo<<<dim3(256), dim3(64), 0, stream>>>(
            pre, w_hh_f, w_hh_b, h_out);
        fc_kernel<<<dim3(128), dim3(64), 0, stream>>>(h_out, w_fc, b_fc, out);
    } else {
        float* h_out = (float*)d_ws;   // 64 KiB
        lstm_scan_fused_kernel<<<dim3(256), dim3(256), 0, stream>>>(
            x, w_ih_f, w_hh_f, b_ih_f, b_hh_f,
            w_ih_b, w_hh_b, b_ih_b, b_hh_b, h_out);
        fc_kernel<<<dim3(128), dim3(64), 0, stream>>>(h_out, w_fc, b_fc, out);
    }
}

// Round 20
// 1817.051 us; speedup vs baseline: 2.1317x; 2.1317x over previous
//
#include <hip/hip_runtime.h>
#include <hip/hip_bf16.h>

#define TT 4096
#define FF 80
#define HH 64
#define NB 128
#define TB 256    // proj: timesteps per block
#define CT 8      // proj: timesteps per staging phase
#define XPAD 104  // proj LDS row stride in bf16 elems
#define LOG2E 1.44269504088896340736f
#define K2E   2.88539008177792681472f   // 2*log2(e)

using short8  = __attribute__((ext_vector_type(8))) short;   // 8 bf16 = 4 VGPR
using floatx4 = __attribute__((ext_vector_type(4))) float;

__device__ __forceinline__ float sigm(float x)  { return __builtin_amdgcn_rcpf(1.0f + __expf(-x)); }
__device__ __forceinline__ float tanh_f(float x){ return 1.0f - 2.0f * __builtin_amdgcn_rcpf(1.0f + __expf(2.0f * x)); }

__device__ __forceinline__ unsigned short f2bf(float f) {    // RNE f32->bf16
    unsigned u = __builtin_bit_cast(unsigned, f);
    u += 0x7fffu + ((u >> 16) & 1u);
    return (unsigned short)(u >> 16);
}
__device__ __forceinline__ float bflo(unsigned u) { return __builtin_bit_cast(float, u << 16); }
__device__ __forceinline__ float bfhi(unsigned u) { return __builtin_bit_cast(float, u & 0xffff0000u); }
__device__ __forceinline__ unsigned packbf2(float a, float b) {
    return (unsigned)f2bf(a) | ((unsigned)f2bf(b) << 16);
}
__device__ __forceinline__ unsigned short cvt_bf16(float f) {
    unsigned r;
    asm("v_cvt_pk_bf16_f32 %0, %1, %2" : "=v"(r) : "v"(f), "v"(f));
    return (unsigned short)r;
}
// LDS-visibility-only barrier: global loads stay in flight across it.
__device__ __forceinline__ void bar_lgkm() {
    asm volatile("s_waitcnt lgkmcnt(0)" ::: "memory");
    __builtin_amdgcn_s_barrier();
}
__device__ __forceinline__ floatx4 mfma16(short8 a, short8 b, floatx4 c) {
    return __builtin_amdgcn_mfma_f32_16x16x32_bf16(a, b, c, 0, 0, 0);
}
// activations on log2e-prescaled inputs (r13, vetted)
__device__ __forceinline__ float sigm_s(float s) {
    return __builtin_amdgcn_rcpf(1.0f + __builtin_amdgcn_exp2f(-s));
}
__device__ __forceinline__ float tanh_s(float s) {
    return fmaf(-2.0f, __builtin_amdgcn_rcpf(1.0f + __builtin_amdgcn_exp2f(s + s)), 1.0f);
}

// ---------------------------------------------------------------------------
// PROJ (MFMA): PRE[chain][t][unit*4 + gatetype] bf16, PRE-SCALED by log2e.
// Identical to round 13/17 (passed every round since r9).
// ---------------------------------------------------------------------------
__global__ __launch_bounds__(256, 1)
void lstm_proj_mfma(const float* __restrict__ x,
                    const float* __restrict__ w_ih_f, const float* __restrict__ b_ih_f,
                    const float* __restrict__ b_hh_f,
                    const float* __restrict__ w_ih_b, const float* __restrict__ b_ih_b,
                    const float* __restrict__ b_hh_b,
                    unsigned short* __restrict__ pre)
{
    const int blk   = blockIdx.x;
    const int ttile = blk & 15;
    const int dgrp  = blk >> 4;
    const int dir   = dgrp >> 3;
    const int bgrp  = dgrp & 7;
    const int tid   = threadIdx.x;
    const int wv    = tid >> 6;
    const int l     = tid & 63;
    const int b16   = l & 15;
    const int g     = l >> 4;
    const int t0    = ttile * TB;

    const float* __restrict__ wih = dir ? w_ih_b : w_ih_f;
    const float* __restrict__ bi  = dir ? b_ih_b : b_ih_f;
    const float* __restrict__ bh  = dir ? b_hh_b : b_hh_f;

    short8 Bf[4][3];
    float  bias[4];
    #pragma unroll
    for (int tp = 0; tp < 4; ++tp) {
        const int n = 64 * wv + 16 * tp + b16;
        bias[tp] = (bi[n] + bh[n]) * LOG2E;
        #pragma unroll
        for (int kap = 0; kap < 3; ++kap) {
            const int f0 = 32 * kap + 8 * g;
            float f[8];
            if (f0 < FF) {
                const float4 v0 = *reinterpret_cast<const float4*>(wih + n * FF + f0);
                const float4 v1 = *reinterpret_cast<const float4*>(wih + n * FF + f0 + 4);
                f[0]=v0.x; f[1]=v0.y; f[2]=v0.z; f[3]=v0.w;
                f[4]=v1.x; f[5]=v1.y; f[6]=v1.z; f[7]=v1.w;
            } else {
                #pragma unroll
                for (int j = 0; j < 8; ++j) f[j] = 0.0f;
            }
            short8 s;
            #pragma unroll
            for (int j = 0; j < 8; ++j) s[j] = (short)f2bf(f[j] * LOG2E);
            Bf[tp][kap] = s;
        }
    }

    __shared__ __align__(16) unsigned short xa[2][CT][16][XPAD];
    for (int i = tid; i < 2 * CT * 16 * XPAD / 2; i += 256)
        reinterpret_cast<unsigned*>(&xa[0][0][0][0])[i] = 0u;
    __syncthreads();

    const int nph = TB / CT;   // 32

    {   // prologue
        const int t0p = t0;
        const int te_base = dir ? (TT - CT - t0p) : t0p;
        float2 st[20];
        #pragma unroll
        for (int q = 0; q < 20; ++q) {
            const int i = q * 256 + tid;
            const int b = i / 320, r2 = i % 320;
            const int te_rel = r2 / 40, fq = r2 % 40;
            st[q] = *reinterpret_cast<const float2*>(
                x + ((size_t)(bgrp * 16 + b) * TT + te_base + te_rel) * FF + 2 * fq);
        }
        #pragma unroll
        for (int q = 0; q < 20; ++q) {
            const int i = q * 256 + tid;
            const int b = i / 320, r2 = i % 320;
            const int te_rel = r2 / 40, fq = r2 % 40;
            const int t_off = dir ? (CT - 1 - te_rel) : te_rel;
            *reinterpret_cast<unsigned*>(&xa[0][t_off][b][2 * fq]) = packbf2(st[q].x, st[q].y);
        }
    }
    __syncthreads();

    #pragma unroll 1
    for (int ph = 0; ph < nph; ++ph) {
        const int cur = ph & 1;
        const bool have = (ph + 1) < nph;

        float2 st[20];
        if (have) {
            const int t0p = t0 + (ph + 1) * CT;
            const int te_base = dir ? (TT - CT - t0p) : t0p;
            #pragma unroll
            for (int q = 0; q < 20; ++q) {
                const int i = q * 256 + tid;
                const int b = i / 320, r2 = i % 320;
                const int te_rel = r2 / 40, fq = r2 % 40;
                st[q] = *reinterpret_cast<const float2*>(
                    x + ((size_t)(bgrp * 16 + b) * TT + te_base + te_rel) * FF + 2 * fq);
            }
        }

        #pragma unroll
        for (int t_off = 0; t_off < CT; ++t_off) {
            short8 A[3];
            #pragma unroll
            for (int kap = 0; kap < 3; ++kap)
                A[kap] = *reinterpret_cast<const short8*>(&xa[cur][t_off][b16][32 * kap + 8 * g]);
            const int t = t0 + ph * CT + t_off;
            #pragma unroll
            for (int tp = 0; tp < 4; ++tp) {
                floatx4 acc = {bias[tp], bias[tp], bias[tp], bias[tp]};
                acc = mfma16(A[0], Bf[tp][0], acc);
                acc = mfma16(A[1], Bf[tp][1], acc);
                acc = mfma16(A[2], Bf[tp][2], acc);
                const int p = (16 * tp + b16) * 4 + wv;   // unit*4 + gatetype
                #pragma unroll
                for (int r = 0; r < 4; ++r) {
                    const int bb = dir * NB + bgrp * 16 + 4 * g + r;
                    pre[((size_t)bb * TT + t) * 256 + p] = f2bf(acc[r]);
                }
            }
        }

        if (have) {
            #pragma unroll
            for (int q = 0; q < 20; ++q) {
                const int i = q * 256 + tid;
                const int b = i / 320, r2 = i % 320;
                const int te_rel = r2 / 40, fq = r2 % 40;
                const int t_off = dir ? (CT - 1 - te_rel) : te_rel;
                *reinterpret_cast<unsigned*>(&xa[cur ^ 1][t_off][b][2 * fq]) = packbf2(st[q].x, st[q].y);
            }
        }
        bar_lgkm();
    }
}

// ---------------------------------------------------------------------------
// SCAN v13 (2-wave): 256 blocks x 128 threads = 2 waves/chain. Wave wv owns
// units 32wv..32wv+31 (8 tiles x 2 K-chunks = 16 MFMAs, 64 VGPR of B-frags —
// fits; r19's 1-wave variant needed 256+ and spilled). The 4->2 wave
// rendezvous halves the per-step barrier skew/drain that dominates r17's
// 672cy step. Cell owners: lanes 0..15 each update TWO independent cells
// (units u0 = 32wv+b16 and u0+16 -> ILP). Everything else byte-identical to
// r17's verified scan: chained MFMA pair, post-MFMA gate add, zero-region A
// addressing, pointer-bump depth-4 rings, c2-domain cell, cvt_pk store, one
// lgkm-only barrier per step.
// LDS bytes: [0,128) h par0, [128,256) h par1, [256,384) zeros.
// ---------------------------------------------------------------------------
__global__ __launch_bounds__(128, 1)
void lstm_scan_w2(const unsigned short* __restrict__ pre,  // [256][TT][256]
                  const float* __restrict__ w_hh_f, const float* __restrict__ w_hh_b,
                  float* __restrict__ h_out)               // [256][64]
{
    const int chain = blockIdx.x;       // dir*128 + bat
    const int dir   = chain >> 7;
    const int tid   = threadIdx.x;      // 0..127
    const int wv    = tid >> 6;         // 0..1 : unit window 32wv..32wv+31
    const int l     = tid & 63;
    const int b16   = l & 15;           // A row / C col
    const int g4    = l >> 4;           // k-group
    const bool actC = (g4 == 0);        // C row-0 lanes (l = 0..15): cell owners
    const int  u0   = 32 * wv + b16;    // first owned unit
    const int  u1   = u0 + 16;          // second owned unit

    const float* __restrict__ whh = dir ? w_hh_b : w_hh_f;

    // B-fragments (log2e-scaled): gate gt, sub-tile tp in {0,1}.
    // col n = gt*64 + 32*wv + 16*tp + b16 ; k = 32*kap + 8*g4 + j
    short8 Bf[4][2][2];
    #pragma unroll
    for (int gt = 0; gt < 4; ++gt) {
        #pragma unroll
        for (int tp = 0; tp < 2; ++tp) {
            const int n = gt * 64 + 32 * wv + 16 * tp + b16;
            #pragma unroll
            for (int kap = 0; kap < 2; ++kap) {
                const float4 v0 = *reinterpret_cast<const float4*>(whh + n * HH + 32 * kap + 8 * g4);
                const float4 v1 = *reinterpret_cast<const float4*>(whh + n * HH + 32 * kap + 8 * g4 + 4);
                short8 s;
                s[0]=(short)f2bf(v0.x*LOG2E); s[1]=(short)f2bf(v0.y*LOG2E);
                s[2]=(short)f2bf(v0.z*LOG2E); s[3]=(short)f2bf(v0.w*LOG2E);
                s[4]=(short)f2bf(v1.x*LOG2E); s[5]=(short)f2bf(v1.y*LOG2E);
                s[6]=(short)f2bf(v1.z*LOG2E); s[7]=(short)f2bf(v1.w*LOG2E);
                Bf[gt][tp][kap] = s;
            }
        }
    }

    // LDS: bytes [0,128) = h par0, [128,256) = h par1, [256,384) = zeros.
    __shared__ __align__(16) unsigned short hls[192];
    if (tid < 96) reinterpret_cast<unsigned*>(hls)[tid] = 0u;

    // PRE rings, one per owned unit (uint2 = {i,f | g,o}), pointer-bump form.
    const uint2* __restrict__ prow0 = reinterpret_cast<const uint2*>(
        pre + (size_t)chain * TT * 256 + u0 * 4);
    const uint2* __restrict__ prow1 = reinterpret_cast<const uint2*>(
        pre + (size_t)chain * TT * 256 + u1 * 4);
    uint2 prA[4] = {{0,0},{0,0},{0,0},{0,0}};
    uint2 prB[4] = {{0,0},{0,0},{0,0},{0,0}};
    const uint2 *pA0 = prow0 + 4*64, *pA1 = prow0 + 5*64, *pA2 = prow0 + 6*64, *pA3 = prow0 + 7*64;
    const uint2 *pB0 = prow1 + 4*64, *pB1 = prow1 + 5*64, *pB2 = prow1 + 6*64, *pB3 = prow1 + 7*64;
    if (actC) {
        prA[0] = prow0[0*64]; prA[1] = prow0[1*64]; prA[2] = prow0[2*64]; prA[3] = prow0[3*64];
        prB[0] = prow1[0*64]; prB[1] = prow1[1*64]; prB[2] = prow1[2*64]; prB[3] = prow1[3*64];
    }

    float c2A = 0.0f, hA = 0.0f;   // c2 = 2*log2e * c
    float c2B = 0.0f, hB = 0.0f;
    __syncthreads();

    const char* lb = reinterpret_cast<const char*>(hls);
    char* lw = reinterpret_cast<char*>(hls);

    #pragma unroll 1
    for (int t = 0; t < TT; t += 4) {
        #pragma unroll
        for (int d = 0; d < 4; ++d) {
            const int cur = d & 1;       // (t+d)&1 since t%4==0

            // A fragments: row-0 lanes read h(t); others read zeros (r9 layout).
            const int abase = (b16 == 0 ? 128 * cur : 256) + 16 * g4;
            const short8 A0 = *reinterpret_cast<const short8*>(lb + abase);
            const short8 A1 = *reinterpret_cast<const short8*>(lb + abase + 64);

            // capture PRE for this step, rotate rings (pointer bump).
            uint2 pcA = prA[d], pcB = prB[d];
            if (actC) {
                if (d == 0)      { prA[0] = *pA0; pA0 += 256; prB[0] = *pB0; pB0 += 256; }
                else if (d == 1) { prA[1] = *pA1; pA1 += 256; prB[1] = *pB1; pB1 += 256; }
                else if (d == 2) { prA[2] = *pA2; pA2 += 256; prB[2] = *pB2; pB2 += 256; }
                else             { prA[3] = *pA3; pA3 += 256; prB[3] = *pB3; pB3 += 256; }
            }

            // G = h @ W_hh^T : 8 tiles (4 gates x 2 sub-tiles), chained pairs
            const floatx4 z = {0.f, 0.f, 0.f, 0.f};
            const floatx4 ci0 = mfma16(A1, Bf[0][0][1], mfma16(A0, Bf[0][0][0], z));
            const floatx4 ci1 = mfma16(A1, Bf[0][1][1], mfma16(A0, Bf[0][1][0], z));
            const floatx4 cf0 = mfma16(A1, Bf[1][0][1], mfma16(A0, Bf[1][0][0], z));
            const floatx4 cf1 = mfma16(A1, Bf[1][1][1], mfma16(A0, Bf[1][1][0], z));
            const floatx4 cg0 = mfma16(A1, Bf[2][0][1], mfma16(A0, Bf[2][0][0], z));
            const floatx4 cg1 = mfma16(A1, Bf[2][1][1], mfma16(A0, Bf[2][1][0], z));
            const floatx4 co0 = mfma16(A1, Bf[3][0][1], mfma16(A0, Bf[3][0][0], z));
            const floatx4 co1 = mfma16(A1, Bf[3][1][1], mfma16(A0, Bf[3][1][0], z));

            if (actC) {
                {   // cell for unit u0
                    const float gi = bflo(pcA.x) + ci0[0];
                    const float gf = bfhi(pcA.x) + cf0[0];
                    const float gg = bflo(pcA.y) + cg0[0];
                    const float go = bfhi(pcA.y) + co0[0];
                    const float si = sigm_s(gi), sf = sigm_s(gf);
                    const float tg = tanh_s(gg), so = sigm_s(go);
                    c2A = fmaf(sf, c2A, K2E * (si * tg));
                    const float th = fmaf(-2.0f,
                        __builtin_amdgcn_rcpf(1.0f + __builtin_amdgcn_exp2f(c2A)), 1.0f);
                    hA = so * th;
                }
                {   // cell for unit u1 (independent -> ILP)
                    const float gi = bflo(pcB.x) + ci1[0];
                    const float gf = bfhi(pcB.x) + cf1[0];
                    const float gg = bflo(pcB.y) + cg1[0];
                    const float go = bfhi(pcB.y) + co1[0];
                    const float si = sigm_s(gi), sf = sigm_s(gf);
                    const float tg = tanh_s(gg), so = sigm_s(go);
                    c2B = fmaf(sf, c2B, K2E * (si * tg));
                    const float th = fmaf(-2.0f,
                        __builtin_amdgcn_rcpf(1.0f + __builtin_amdgcn_exp2f(c2B)), 1.0f);
                    hB = so * th;
                }
                *reinterpret_cast<unsigned short*>(lw + 128 * (cur ^ 1) + 2 * u0) = cvt_bf16(hA);
                *reinterpret_cast<unsigned short*>(lw + 128 * (cur ^ 1) + 2 * u1) = cvt_bf16(hB);
            }
            bar_lgkm();                  // 2-wave rendezvous (was 4-wave in r17)
        }
    }

    if (actC) {
        h_out[(size_t)chain * HH + u0] = hA;
        h_out[(size_t)chain * HH + u1] = hB;
    }
}

// ---------------------------------------------------------------------------
// Fallback: fully fused scan (round-1 kernel) if ws is too small for PRE.
// ---------------------------------------------------------------------------
__global__ __launch_bounds__(256, 1)
void lstm_scan_fused_kernel(const float* __restrict__ x,
                            const float* __restrict__ w_ih_f, const float* __restrict__ w_hh_f,
                            const float* __restrict__ b_ih_f, const float* __restrict__ b_hh_f,
                            const float* __restrict__ w_ih_b, const float* __restrict__ w_hh_b,
                            const float* __restrict__ b_ih_b, const float* __restrict__ b_hh_b,
                            float* __restrict__ h_out)
{
    const int blk = blockIdx.x;
    const int dir = blk >> 7;
    const int bat = blk & 127;
    const int tid = threadIdx.x;
    const int wv  = tid >> 6;
    const int ln  = tid & 63;

    const float* __restrict__ w_ih = dir ? w_ih_b : w_ih_f;
    const float* __restrict__ w_hh = dir ? w_hh_b : w_hh_f;
    const float* __restrict__ b_ih = dir ? b_ih_b : b_ih_f;
    const float* __restrict__ b_hh = dir ? b_hh_b : b_hh_f;

    float wi[FF], wh[HH];
    #pragma unroll
    for (int f = 0; f < FF; ++f) wi[f] = w_ih[tid * FF + f];
    #pragma unroll
    for (int j = 0; j < HH; ++j) wh[j] = w_hh[tid * HH + j];
    const float bias = b_ih[tid] + b_hh[tid];

    __shared__ float xs[2][FF];
    __shared__ float hbuf[4][HH];
    __shared__ float gbuf[2][256];

    const float* __restrict__ xrow = x + (size_t)bat * (TT * FF);
    float c = 0.0f, hreg = 0.0f;
    hbuf[wv][ln] = 0.0f;

    float xA = 0.0f;
    if (tid < FF) {
        xs[0][tid] = xrow[(size_t)(dir ? (TT - 1) : 0) * FF + tid];
        xA         = xrow[(size_t)(dir ? (TT - 2) : 1) * FF + tid];
    }
    __syncthreads();

    #pragma unroll 1
    for (int t = 0; t < TT; ++t) {
        const int cur = t & 1, nxt = cur ^ 1;
        float a0 = 0.f, a1 = 0.f, a2 = 0.f, a3 = 0.f;
        const float4* xs4 = reinterpret_cast<const float4*>(xs[cur]);
        #pragma unroll
        for (int f = 0; f < FF / 4; ++f) {
            float4 v = xs4[f];
            a0 = fmaf(wi[4*f+0], v.x, a0);
            a1 = fmaf(wi[4*f+1], v.y, a1);
            a2 = fmaf(wi[4*f+2], v.z, a2);
            a3 = fmaf(wi[4*f+3], v.w, a3);
        }
        const float4* hb4 = reinterpret_cast<const float4*>(hbuf[wv]);
        #pragma unroll
        for (int j = 0; j < HH / 4; ++j) {
            float4 v = hb4[j];
            a0 = fmaf(wh[4*j+0], v.x, a0);
            a1 = fmaf(wh[4*j+1], v.y, a1);
            a2 = fmaf(wh[4*j+2], v.z, a2);
            a3 = fmaf(wh[4*j+3], v.w, a3);
        }
        gbuf[cur][tid] = ((a0 + a1) + (a2 + a3)) + bias;

        if (tid < FF) {
            if (t + 1 < TT) xs[nxt][tid] = xA;
            if (t + 2 < TT) xA = xrow[(size_t)(dir ? (TT - 3 - t) : (t + 2)) * FF + tid];
        }
        __syncthreads();

        const float gi = gbuf[cur][ln];
        const float gf = gbuf[cur][64 + ln];
        const float gg = gbuf[cur][128 + ln];
        const float go = gbuf[cur][192 + ln];
        c    = sigm(gf) * c + sigm(gi) * tanh_f(gg);
        hreg = sigm(go) * tanh_f(c);
        hbuf[wv][ln] = hreg;
    }

    if (tid < HH) h_out[(size_t)(dir * 128 + bat) * HH + tid] = hreg;
}

__global__ __launch_bounds__(64, 1)
void fc_kernel(const float* __restrict__ h_out,   // [2][NB][HH]
               const float* __restrict__ w_fc,    // [8][128]
               const float* __restrict__ b_fc,    // [8]
               float* __restrict__ out)           // [NB][8]
{
    const int b = blockIdx.x;
    const int o = threadIdx.x;
    if (o < 8) {
        float acc = b_fc[o];
        #pragma unroll 4
        for (int j = 0; j < HH; ++j)
            acc = fmaf(h_out[(size_t)b * HH + j], w_fc[o * 128 + j], acc);
        #pragma unroll 4
        for (int j = 0; j < HH; ++j)
            acc = fmaf(h_out[(size_t)(NB + b) * HH + j], w_fc[o * 128 + 64 + j], acc);
        out[b * 8 + o] = acc;
    }
}

extern "C" void kernel_launch(void* const* d_in, const int* in_sizes, int n_in,
                              void* d_out, int out_size, void* d_ws, size_t ws_size,
                              hipStream_t stream) {
    const float* x      = (const float*)d_in[0];
    const float* w_ih_f = (const float*)d_in[2];
    const float* w_hh_f = (const float*)d_in[3];
    const float* b_ih_f = (const float*)d_in[4];
    const float* b_hh_f = (const float*)d_in[5];
    const float* w_ih_b = (const float*)d_in[6];
    const float* w_hh_b = (const float*)d_in[7];
    const float* b_ih_b = (const float*)d_in[8];
    const float* b_hh_b = (const float*)d_in[9];
    const float* w_fc   = (const float*)d_in[10];
    const float* b_fc   = (const float*)d_in[11];
    float* out = (float*)d_out;

    const size_t pre_bytes = (size_t)2 * NB * TT * 256 * 2;   // 512 MiB bf16
    const size_t need      = pre_bytes + 64 * 1024;

    if (ws_size >= need) {
        unsigned short* pre = (unsigned short*)d_ws;
        float* h_out = (float*)((char*)d_ws + pre_bytes);
        lstm_proj_mfma<<<dim3(256), dim3(256), 0, stream>>>(
            x, w_ih_f, b_ih_f, b_hh_f, w_ih_b, b_ih_b, b_hh_b, pre);
        lstm_scan_w2<<<dim3(256), dim3(128), 0, stream>>>(
            pre, w_hh_f, w_hh_b, h_out);
        fc_kernel<<<dim3(128), dim3(64), 0, stream>>>(h_out, w_fc, b_fc, out);
    } else {
        float* h_out = (float*)d_ws;   // 64 KiB
        lstm_scan_fused_kernel<<<dim3(256), dim3(256), 0, stream>>>(
            x, w_ih_f, w_hh_f, b_ih_f, b_hh_f,
            w_ih_b, w_hh_b, b_ih_b, b_hh_b, h_out);
        fc_kernel<<<dim3(128), dim3(64), 0, stream>>>(h_out, w_fc, b_fc, out);
    }
}

// Round 21
// 1326.364 us; speedup vs baseline: 2.9204x; 1.3699x over previous
//
#include <hip/hip_runtime.h>
#include <hip/hip_bf16.h>

#define TT 4096
#define FF 80
#define HH 64
#define NB 128
#define TB 256    // proj: timesteps per block
#define CT 8      // proj: timesteps per staging phase
#define XPAD 104  // proj LDS row stride in bf16 elems
#define LOG2E 1.44269504088896340736f
#define K2E   2.88539008177792681472f   // 2*log2(e)

using short8  = __attribute__((ext_vector_type(8))) short;   // 8 bf16 = 4 VGPR
using floatx4 = __attribute__((ext_vector_type(4))) float;

__device__ __forceinline__ float sigm(float x)  { return __builtin_amdgcn_rcpf(1.0f + __expf(-x)); }
__device__ __forceinline__ float tanh_f(float x){ return 1.0f - 2.0f * __builtin_amdgcn_rcpf(1.0f + __expf(2.0f * x)); }

__device__ __forceinline__ unsigned short f2bf(float f) {    // RNE f32->bf16
    unsigned u = __builtin_bit_cast(unsigned, f);
    u += 0x7fffu + ((u >> 16) & 1u);
    return (unsigned short)(u >> 16);
}
__device__ __forceinline__ float bflo(unsigned u) { return __builtin_bit_cast(float, u << 16); }
__device__ __forceinline__ float bfhi(unsigned u) { return __builtin_bit_cast(float, u & 0xffff0000u); }
__device__ __forceinline__ unsigned packbf2(float a, float b) {
    return (unsigned)f2bf(a) | ((unsigned)f2bf(b) << 16);
}

// single-instruction f32->bf16 (RNE) for the critical path
__device__ __forceinline__ unsigned short cvt_bf16(float f) {
    unsigned r;
    asm("v_cvt_pk_bf16_f32 %0, %1, %2" : "=v"(r) : "v"(f), "v"(f));
    return (unsigned short)r;
}

// LDS-visibility-only barrier: global loads stay in flight across it.
__device__ __forceinline__ void bar_lgkm() {
    asm volatile("s_waitcnt lgkmcnt(0)" ::: "memory");
    __builtin_amdgcn_s_barrier();
}

__device__ __forceinline__ floatx4 mfma16(short8 a, short8 b, floatx4 c) {
    return __builtin_amdgcn_mfma_f32_16x16x32_bf16(a, b, c, 0, 0, 0);
}

// activations on log2e-prescaled inputs (r13, vetted)
__device__ __forceinline__ float sigm_s(float s) {
    return __builtin_amdgcn_rcpf(1.0f + __builtin_amdgcn_exp2f(-s));
}
__device__ __forceinline__ float tanh_s(float s) {
    return fmaf(-2.0f, __builtin_amdgcn_rcpf(1.0f + __builtin_amdgcn_exp2f(s + s)), 1.0f);
}

// ---------------------------------------------------------------------------
// PROJ (MFMA): PRE[chain][t][unit*4 + gatetype] bf16, PRE-SCALED by log2e.
// Identical to round 13/17 (passed every round since r9).
// ---------------------------------------------------------------------------
__global__ __launch_bounds__(256, 1)
void lstm_proj_mfma(const float* __restrict__ x,
                    const float* __restrict__ w_ih_f, const float* __restrict__ b_ih_f,
                    const float* __restrict__ b_hh_f,
                    const float* __restrict__ w_ih_b, const float* __restrict__ b_ih_b,
                    const float* __restrict__ b_hh_b,
                    unsigned short* __restrict__ pre)
{
    const int blk   = blockIdx.x;
    const int ttile = blk & 15;
    const int dgrp  = blk >> 4;
    const int dir   = dgrp >> 3;
    const int bgrp  = dgrp & 7;
    const int tid   = threadIdx.x;
    const int wv    = tid >> 6;
    const int l     = tid & 63;
    const int b16   = l & 15;
    const int g     = l >> 4;
    const int t0    = ttile * TB;

    const float* __restrict__ wih = dir ? w_ih_b : w_ih_f;
    const float* __restrict__ bi  = dir ? b_ih_b : b_ih_f;
    const float* __restrict__ bh  = dir ? b_hh_b : b_hh_f;

    short8 Bf[4][3];
    float  bias[4];
    #pragma unroll
    for (int tp = 0; tp < 4; ++tp) {
        const int n = 64 * wv + 16 * tp + b16;
        bias[tp] = (bi[n] + bh[n]) * LOG2E;
        #pragma unroll
        for (int kap = 0; kap < 3; ++kap) {
            const int f0 = 32 * kap + 8 * g;
            float f[8];
            if (f0 < FF) {
                const float4 v0 = *reinterpret_cast<const float4*>(wih + n * FF + f0);
                const float4 v1 = *reinterpret_cast<const float4*>(wih + n * FF + f0 + 4);
                f[0]=v0.x; f[1]=v0.y; f[2]=v0.z; f[3]=v0.w;
                f[4]=v1.x; f[5]=v1.y; f[6]=v1.z; f[7]=v1.w;
            } else {
                #pragma unroll
                for (int j = 0; j < 8; ++j) f[j] = 0.0f;
            }
            short8 s;
            #pragma unroll
            for (int j = 0; j < 8; ++j) s[j] = (short)f2bf(f[j] * LOG2E);
            Bf[tp][kap] = s;
        }
    }

    __shared__ __align__(16) unsigned short xa[2][CT][16][XPAD];
    for (int i = tid; i < 2 * CT * 16 * XPAD / 2; i += 256)
        reinterpret_cast<unsigned*>(&xa[0][0][0][0])[i] = 0u;
    __syncthreads();

    const int nph = TB / CT;   // 32

    {   // prologue
        const int t0p = t0;
        const int te_base = dir ? (TT - CT - t0p) : t0p;
        float2 st[20];
        #pragma unroll
        for (int q = 0; q < 20; ++q) {
            const int i = q * 256 + tid;
            const int b = i / 320, r2 = i % 320;
            const int te_rel = r2 / 40, fq = r2 % 40;
            st[q] = *reinterpret_cast<const float2*>(
                x + ((size_t)(bgrp * 16 + b) * TT + te_base + te_rel) * FF + 2 * fq);
        }
        #pragma unroll
        for (int q = 0; q < 20; ++q) {
            const int i = q * 256 + tid;
            const int b = i / 320, r2 = i % 320;
            const int te_rel = r2 / 40, fq = r2 % 40;
            const int t_off = dir ? (CT - 1 - te_rel) : te_rel;
            *reinterpret_cast<unsigned*>(&xa[0][t_off][b][2 * fq]) = packbf2(st[q].x, st[q].y);
        }
    }
    __syncthreads();

    #pragma unroll 1
    for (int ph = 0; ph < nph; ++ph) {
        const int cur = ph & 1;
        const bool have = (ph + 1) < nph;

        float2 st[20];
        if (have) {
            const int t0p = t0 + (ph + 1) * CT;
            const int te_base = dir ? (TT - CT - t0p) : t0p;
            #pragma unroll
            for (int q = 0; q < 20; ++q) {
                const int i = q * 256 + tid;
                const int b = i / 320, r2 = i % 320;
                const int te_rel = r2 / 40, fq = r2 % 40;
                st[q] = *reinterpret_cast<const float2*>(
                    x + ((size_t)(bgrp * 16 + b) * TT + te_base + te_rel) * FF + 2 * fq);
            }
        }

        #pragma unroll
        for (int t_off = 0; t_off < CT; ++t_off) {
            short8 A[3];
            #pragma unroll
            for (int kap = 0; kap < 3; ++kap)
                A[kap] = *reinterpret_cast<const short8*>(&xa[cur][t_off][b16][32 * kap + 8 * g]);
            const int t = t0 + ph * CT + t_off;
            #pragma unroll
            for (int tp = 0; tp < 4; ++tp) {
                floatx4 acc = {bias[tp], bias[tp], bias[tp], bias[tp]};
                acc = mfma16(A[0], Bf[tp][0], acc);
                acc = mfma16(A[1], Bf[tp][1], acc);
                acc = mfma16(A[2], Bf[tp][2], acc);
                const int p = (16 * tp + b16) * 4 + wv;   // unit*4 + gatetype
                #pragma unroll
                for (int r = 0; r < 4; ++r) {
                    const int bb = dir * NB + bgrp * 16 + 4 * g + r;
                    pre[((size_t)bb * TT + t) * 256 + p] = f2bf(acc[r]);
                }
            }
        }

        if (have) {
            #pragma unroll
            for (int q = 0; q < 20; ++q) {
                const int i = q * 256 + tid;
                const int b = i / 320, r2 = i % 320;
                const int te_rel = r2 / 40, fq = r2 % 40;
                const int t_off = dir ? (CT - 1 - te_rel) : te_rel;
                *reinterpret_cast<unsigned*>(&xa[cur ^ 1][t_off][b][2 * fq]) = packbf2(st[q].x, st[q].y);
            }
        }
        bar_lgkm();
    }
}

// ---------------------------------------------------------------------------
// SCAN (champion, = round 17, measured 1145 us): 256 blocks x 4 waves,
// 1 chain/CU. Chained MFMA pair, post-MFMA gate add, zero-region A
// addressing, pointer-bump depth-4 PRE ring, c2-domain cell, cvt_pk store,
// one lgkm-only barrier per step.
// ---------------------------------------------------------------------------
__global__ __launch_bounds__(256, 1)
void lstm_scan_mfma7(const unsigned short* __restrict__ pre,  // [256][TT][256]
                     const float* __restrict__ w_hh_f, const float* __restrict__ w_hh_b,
                     float* __restrict__ h_out)               // [256][64]
{
    const int chain = blockIdx.x;       // dir*128 + bat
    const int dir   = chain >> 7;
    const int tid   = threadIdx.x;
    const int wv    = tid >> 6;         // unit window: 16*wv .. 16*wv+15
    const int l     = tid & 63;
    const int b16   = l & 15;           // A row / C col
    const int g4    = l >> 4;           // k-group
    const bool actC = (g4 == 0);        // C row-0 lanes (l = 0..15): cell owners
    const int  u    = 16 * wv + b16;    // this lane's unit (valid when actC)

    const float* __restrict__ whh = dir ? w_hh_b : w_hh_f;

    // B-fragments (scaled by log2e): gate gt (0:i 1:f 2:g 3:o), kap (K chunk).
    short8 Bf[4][2];
    #pragma unroll
    for (int gt = 0; gt < 4; ++gt) {
        const int n = gt * 64 + 16 * wv + b16;
        #pragma unroll
        for (int kap = 0; kap < 2; ++kap) {
            const float4 v0 = *reinterpret_cast<const float4*>(whh + n * HH + 32 * kap + 8 * g4);
            const float4 v1 = *reinterpret_cast<const float4*>(whh + n * HH + 32 * kap + 8 * g4 + 4);
            short8 s;
            s[0]=(short)f2bf(v0.x*LOG2E); s[1]=(short)f2bf(v0.y*LOG2E);
            s[2]=(short)f2bf(v0.z*LOG2E); s[3]=(short)f2bf(v0.w*LOG2E);
            s[4]=(short)f2bf(v1.x*LOG2E); s[5]=(short)f2bf(v1.y*LOG2E);
            s[6]=(short)f2bf(v1.z*LOG2E); s[7]=(short)f2bf(v1.w*LOG2E);
            Bf[gt][kap] = s;
        }
    }

    // LDS: bytes [0,128) = h buf0 (bf16[64]), [128,256) = h buf1,
    //      [256,384) = permanently-zero region (A rows 1-15 read here).
    __shared__ __align__(16) unsigned short hls[192];
    if (tid < 96) reinterpret_cast<unsigned*>(hls)[tid] = 0u;

    // PRE ring: actC lanes read uint2 = {i,f | g,o} bf16 at [chain][t][u*4].
    // 4 pre-offset pointers, each bumped +4*512B per ring cycle (no recompute).
    const uint2* __restrict__ prow = reinterpret_cast<const uint2*>(
        pre + (size_t)chain * TT * 256 + u * 4);
    uint2 prr[4] = {{0,0},{0,0},{0,0},{0,0}};
    const uint2* pp0 = prow + 4 * 64;
    const uint2* pp1 = prow + 5 * 64;
    const uint2* pp2 = prow + 6 * 64;
    const uint2* pp3 = prow + 7 * 64;
    if (actC) {
        prr[0] = prow[0 * 64];
        prr[1] = prow[1 * 64];
        prr[2] = prow[2 * 64];
        prr[3] = prow[3 * 64];
    }

    float c2 = 0.0f, h = 0.0f;   // c2 = 2*log2e * c
    __syncthreads();

    const char* lb = reinterpret_cast<const char*>(hls);
    char* lw = reinterpret_cast<char*>(hls);

    #pragma unroll 1
    for (int t = 0; t < TT; t += 4) {
        #pragma unroll
        for (int d = 0; d < 4; ++d) {
            const int cur = d & 1;       // (t+d)&1 since t%4==0

            // A fragments: row-0 lanes read h(t); others read zeros (r9/r13 layout).
            const int abase = (b16 == 0 ? 128 * cur : 256) + 16 * g4;
            const short8 A0 = *reinterpret_cast<const short8*>(lb + abase);
            const short8 A1 = *reinterpret_cast<const short8*>(lb + abase + 64);

            // capture PRE for this step, then reload ring slot (pointer bump).
            uint2 pc = prr[d];
            if (actC) {
                if (d == 0)      { prr[0] = *pp0; pp0 += 256; }
                else if (d == 1) { prr[1] = *pp1; pp1 += 256; }
                else if (d == 2) { prr[2] = *pp2; pp2 += 256; }
                else             { prr[3] = *pp3; pp3 += 256; }
            }

            // G = h @ W_hh^T (chained MFMA pair; PRE added after — r16 proved
            // C-in puts the ring decode on the MFMA's critical path)
            const floatx4 z = {0.f, 0.f, 0.f, 0.f};
            const floatx4 ci = mfma16(A1, Bf[0][1], mfma16(A0, Bf[0][0], z));
            const floatx4 cf = mfma16(A1, Bf[1][1], mfma16(A0, Bf[1][0], z));
            const floatx4 cg = mfma16(A1, Bf[2][1], mfma16(A0, Bf[2][0], z));
            const floatx4 co = mfma16(A1, Bf[3][1], mfma16(A0, Bf[3][0], z));

            if (actC) {
                const float gi = bflo(pc.x) + ci[0];    // log2e-scaled gates
                const float gf = bfhi(pc.x) + cf[0];
                const float gg = bflo(pc.y) + cg[0];
                const float go = bfhi(pc.y) + co[0];
                const float si = sigm_s(gi);
                const float sf = sigm_s(gf);
                const float tg = tanh_s(gg);
                const float so = sigm_s(go);
                c2 = fmaf(sf, c2, K2E * (si * tg));     // c2 = 2log2e * c
                const float th = fmaf(-2.0f,
                    __builtin_amdgcn_rcpf(1.0f + __builtin_amdgcn_exp2f(c2)), 1.0f);
                h = so * th;
                *reinterpret_cast<unsigned short*>(lw + 128 * (cur ^ 1) + 2 * u) = cvt_bf16(h);
            }
            bar_lgkm();                  // LDS visibility only; ring stays in flight
        }
    }

    if (actC) h_out[(size_t)chain * HH + u] = h;
}

// ---------------------------------------------------------------------------
// Fallback: fully fused scan (round-1 kernel) if ws is too small for PRE.
// ---------------------------------------------------------------------------
__global__ __launch_bounds__(256, 1)
void lstm_scan_fused_kernel(const float* __restrict__ x,
                            const float* __restrict__ w_ih_f, const float* __restrict__ w_hh_f,
                            const float* __restrict__ b_ih_f, const float* __restrict__ b_hh_f,
                            const float* __restrict__ w_ih_b, const float* __restrict__ w_hh_b,
                            const float* __restrict__ b_ih_b, const float* __restrict__ b_hh_b,
                            float* __restrict__ h_out)
{
    const int blk = blockIdx.x;
    const int dir = blk >> 7;
    const int bat = blk & 127;
    const int tid = threadIdx.x;
    const int wv  = tid >> 6;
    const int ln  = tid & 63;

    const float* __restrict__ w_ih = dir ? w_ih_b : w_ih_f;
    const float* __restrict__ w_hh = dir ? w_hh_b : w_hh_f;
    const float* __restrict__ b_ih = dir ? b_ih_b : b_ih_f;
    const float* __restrict__ b_hh = dir ? b_hh_b : b_hh_f;

    float wi[FF], wh[HH];
    #pragma unroll
    for (int f = 0; f < FF; ++f) wi[f] = w_ih[tid * FF + f];
    #pragma unroll
    for (int j = 0; j < HH; ++j) wh[j] = w_hh[tid * HH + j];
    const float bias = b_ih[tid] + b_hh[tid];

    __shared__ float xs[2][FF];
    __shared__ float hbuf[4][HH];
    __shared__ float gbuf[2][256];

    const float* __restrict__ xrow = x + (size_t)bat * (TT * FF);
    float c = 0.0f, hreg = 0.0f;
    hbuf[wv][ln] = 0.0f;

    float xA = 0.0f;
    if (tid < FF) {
        xs[0][tid] = xrow[(size_t)(dir ? (TT - 1) : 0) * FF + tid];
        xA         = xrow[(size_t)(dir ? (TT - 2) : 1) * FF + tid];
    }
    __syncthreads();

    #pragma unroll 1
    for (int t = 0; t < TT; ++t) {
        const int cur = t & 1, nxt = cur ^ 1;
        float a0 = 0.f, a1 = 0.f, a2 = 0.f, a3 = 0.f;
        const float4* xs4 = reinterpret_cast<const float4*>(xs[cur]);
        #pragma unroll
        for (int f = 0; f < FF / 4; ++f) {
            float4 v = xs4[f];
            a0 = fmaf(wi[4*f+0], v.x, a0);
            a1 = fmaf(wi[4*f+1], v.y, a1);
            a2 = fmaf(wi[4*f+2], v.z, a2);
            a3 = fmaf(wi[4*f+3], v.w, a3);
        }
        const float4* hb4 = reinterpret_cast<const float4*>(hbuf[wv]);
        #pragma unroll
        for (int j = 0; j < HH / 4; ++j) {
            float4 v = hb4[j];
            a0 = fmaf(wh[4*j+0], v.x, a0);
            a1 = fmaf(wh[4*j+1], v.y, a1);
            a2 = fmaf(wh[4*j+2], v.z, a2);
            a3 = fmaf(wh[4*j+3], v.w, a3);
        }
        gbuf[cur][tid] = ((a0 + a1) + (a2 + a3)) + bias;

        if (tid < FF) {
            if (t + 1 < TT) xs[nxt][tid] = xA;
            if (t + 2 < TT) xA = xrow[(size_t)(dir ? (TT - 3 - t) : (t + 2)) * FF + tid];
        }
        __syncthreads();

        const float gi = gbuf[cur][ln];
        const float gf = gbuf[cur][64 + ln];
        const float gg = gbuf[cur][128 + ln];
        const float go = gbuf[cur][192 + ln];
        c    = sigm(gf) * c + sigm(gi) * tanh_f(gg);
        hreg = sigm(go) * tanh_f(c);
        hbuf[wv][ln] = hreg;
    }

    if (tid < HH) h_out[(size_t)(dir * 128 + bat) * HH + tid] = hreg;
}

__global__ __launch_bounds__(64, 1)
void fc_kernel(const float* __restrict__ h_out,   // [2][NB][HH]
               const float* __restrict__ w_fc,    // [8][128]
               const float* __restrict__ b_fc,    // [8]
               float* __restrict__ out)           // [NB][8]
{
    const int b = blockIdx.x;
    const int o = threadIdx.x;
    if (o < 8) {
        float acc = b_fc[o];
        #pragma unroll 4
        for (int j = 0; j < HH; ++j)
            acc = fmaf(h_out[(size_t)b * HH + j], w_fc[o * 128 + j], acc);
        #pragma unroll 4
        for (int j = 0; j < HH; ++j)
            acc = fmaf(h_out[(size_t)(NB + b) * HH + j], w_fc[o * 128 + 64 + j], acc);
        out[b * 8 + o] = acc;
    }
}

extern "C" void kernel_launch(void* const* d_in, const int* in_sizes, int n_in,
                              void* d_out, int out_size, void* d_ws, size_t ws_size,
                              hipStream_t stream) {
    const float* x      = (const float*)d_in[0];
    const float* w_ih_f = (const float*)d_in[2];
    const float* w_hh_f = (const float*)d_in[3];
    const float* b_ih_f = (const float*)d_in[4];
    const float* b_hh_f = (const float*)d_in[5];
    const float* w_ih_b = (const float*)d_in[6];
    const float* w_hh_b = (const float*)d_in[7];
    const float* b_ih_b = (const float*)d_in[8];
    const float* b_hh_b = (const float*)d_in[9];
    const float* w_fc   = (const float*)d_in[10];
    const float* b_fc   = (const float*)d_in[11];
    float* out = (float*)d_out;

    const size_t pre_bytes = (size_t)2 * NB * TT * 256 * 2;   // 512 MiB bf16
    const size_t need      = pre_bytes + 64 * 1024;

    if (ws_size >= need) {
        unsigned short* pre = (unsigned short*)d_ws;
        float* h_out = (float*)((char*)d_ws + pre_bytes);
        lstm_proj_mfma<<<dim3(256), dim3(256), 0, stream>>>(
            x, w_ih_f, b_ih_f, b_hh_f, w_ih_b, b_ih_b, b_hh_b, pre);
        lstm_scan_mfma7<<<dim3(256), dim3(256), 0, stream>>>(
            pre, w_hh_f, w_hh_b, h_out);
        fc_kernel<<<dim3(128), dim3(64), 0, stream>>>(h_out, w_fc, b_fc, out);
    } else {
        float* h_out = (float*)d_ws;   // 64 KiB
        lstm_scan_fused_kernel<<<dim3(256), dim3(256), 0, stream>>>(
            x, w_ih_f, w_hh_f, b_ih_f, b_hh_f,
            w_ih_b, w_hh_b, b_ih_b, b_hh_b, h_out);
        fc_kernel<<<dim3(128), dim3(64), 0, stream>>>(h_out, w_fc, b_fc, out);
    }
}